// Round 8
// baseline (19892.944 us; speedup 1.0000x reference)
//
#include <hip/hip_runtime.h>
#include <hip/hip_bf16.h>

#define TT 256
#define D 1024
#define BD (128 * 1024)
#define CHUNK 128
#define APAD 136

typedef __attribute__((ext_vector_type(8))) short bf16x8;
typedef __attribute__((ext_vector_type(4))) float f32x4;
typedef unsigned long long ull;

__device__ __forceinline__ unsigned short f2bf(float f) {
    __hip_bfloat16 h = __float2bfloat16(f);
    return *reinterpret_cast<unsigned short*>(&h);
}
__device__ __forceinline__ float bf2f(unsigned short u) {
    unsigned v = (unsigned)u << 16;
    return __builtin_bit_cast(float, v);
}

__global__ __launch_bounds__(256) void cvt_f32_bf16(const float* __restrict__ in,
                                                    unsigned short* __restrict__ out, int n) {
    int i = (blockIdx.x * 256 + threadIdx.x) * 8;
    if (i + 8 <= n) {
        float4 a = *(const float4*)(in + i);
        float4 b = *(const float4*)(in + i + 4);
        unsigned short t[8] = { f2bf(a.x), f2bf(a.y), f2bf(a.z), f2bf(a.w),
                                f2bf(b.x), f2bf(b.y), f2bf(b.z), f2bf(b.w) };
        *(uint4*)(out + i) = *(const uint4*)t;
    }
}

#define MF(a, b, c) __builtin_amdgcn_mfma_f32_16x16x32_bf16(a, b, c, 0, 0, 0)
#define SB __builtin_amdgcn_sched_barrier(0)
#define AGLD(p) __hip_atomic_load((p), __ATOMIC_RELAXED, __HIP_MEMORY_SCOPE_AGENT)
#define AGST(p, v) __hip_atomic_store((p), (v), __ATOMIC_RELAXED, __HIP_MEMORY_SCOPE_AGENT)
// light barrier: LDS visibility only; leaves global prefetches in flight
#define LBAR { SB; asm volatile("s_waitcnt lgkmcnt(0)"); __builtin_amdgcn_s_barrier(); SB; }

// stage chunk KC of hin(+x cvt) and hprev into registers (agent-coherent)
#define STAGE_ISSUE(KC) { \
    if (layer == 0) { \
        _Pragma("unroll") for (int i_ = 0; i_ < 8; ++i_) { \
            float4 v_ = *(const float4*)(xsrc + (KC) * CHUNK + i_ * 4); \
            Sh[i_] = (ull)f2bf(v_.x) | ((ull)f2bf(v_.y) << 16) | \
                     ((ull)f2bf(v_.z) << 32) | ((ull)f2bf(v_.w) << 48); \
        } \
    } else { \
        _Pragma("unroll") for (int i_ = 0; i_ < 8; ++i_) \
            Sh[i_] = AGLD(hsrc + (KC) * 32 + i_); \
    } \
    _Pragma("unroll") for (int i_ = 0; i_ < 8; ++i_) \
        Sp[i_] = AGLD(psrc + (KC) * 32 + i_); \
    SB; }

#define STAGE_WRITE(BUF) { \
    _Pragma("unroll") for (int i_ = 0; i_ < 4; ++i_) { \
        uint4 wv_; \
        wv_.x = (unsigned)Sh[i_ * 2];     wv_.y = (unsigned)(Sh[i_ * 2] >> 32); \
        wv_.z = (unsigned)Sh[i_ * 2 + 1]; wv_.w = (unsigned)(Sh[i_ * 2 + 1] >> 32); \
        *(uint4*)&sA[BUF][0][srow][skp + i_ * 8] = wv_; \
        uint4 pv_; \
        pv_.x = (unsigned)Sp[i_ * 2];     pv_.y = (unsigned)(Sp[i_ * 2] >> 32); \
        pv_.z = (unsigned)Sp[i_ * 2 + 1]; pv_.w = (unsigned)(Sp[i_ * 2 + 1] >> 32); \
        *(uint4*)&sA[BUF][1][srow][skp + i_ * 8] = pv_; \
    } SB; }

#define WISSUE(W, KG) { \
    const int ko_ = (KG) * 32; \
    _Pragma("unroll") for (int m_ = 0; m_ < 6; ++m_) { \
        W[m_ * 2 + 0] = *(const bf16x8*)(msrc[m_] + vcol0 + ko_); \
        W[m_ * 2 + 1] = *(const bf16x8*)(msrc[m_] + vcol1 + ko_); \
    } SB; }

#define COMP(BUF, KSL, W) { \
    bf16x8 a00 = *(const bf16x8*)&sA[BUF][0][wrow +  0 + r15][(KSL) * 32 + kq8]; \
    bf16x8 a01 = *(const bf16x8*)&sA[BUF][1][wrow +  0 + r15][(KSL) * 32 + kq8]; \
    bf16x8 a10 = *(const bf16x8*)&sA[BUF][0][wrow + 16 + r15][(KSL) * 32 + kq8]; \
    bf16x8 a11 = *(const bf16x8*)&sA[BUF][1][wrow + 16 + r15][(KSL) * 32 + kq8]; \
    _Pragma("unroll") for (int m_ = 0; m_ < 3; ++m_) { \
        acc[0][0][m_] = MF(a00, W[m_ * 2 + 0], acc[0][0][m_]); \
        acc[0][1][m_] = MF(a00, W[m_ * 2 + 1], acc[0][1][m_]); \
        acc[1][0][m_] = MF(a10, W[m_ * 2 + 0], acc[1][0][m_]); \
        acc[1][1][m_] = MF(a10, W[m_ * 2 + 1], acc[1][1][m_]); } \
    _Pragma("unroll") for (int m_ = 3; m_ < 6; ++m_) { \
        acc[0][0][m_] = MF(a01, W[m_ * 2 + 0], acc[0][0][m_]); \
        acc[0][1][m_] = MF(a01, W[m_ * 2 + 1], acc[0][1][m_]); \
        acc[1][0][m_] = MF(a11, W[m_ * 2 + 0], acc[1][0][m_]); \
        acc[1][1][m_] = MF(a11, W[m_ * 2 + 1], acc[1][1][m_]); } \
    SB; }

#define EPI_ISSUE { \
    _Pragma("unroll") for (int ct_ = 0; ct_ < 2; ++ct_) \
    _Pragma("unroll") for (int rt_ = 0; rt_ < 2; ++rt_) \
    _Pragma("unroll") for (int q_ = 0; q_ < 4; ++q_) { \
        const size_t idx_ = (size_t)(rbase + wrow + rt_ * 16 + kq * 4 + q_) * D + \
                            (c0 + wcol + ct_ * 16 + r15); \
        hpv[ct_][rt_][q_] = AGLD(hprevf + idx_); \
        if (layer == 0) rsl0[ct_][rt_][q_] = xt[idx_]; \
        else rpk[ct_][rt_][q_] = AGLD((const unsigned*)(hinb + (idx_ & ~(size_t)1))); \
    } SB; }

// 96 persistent WGs = 3 layers x 16 col-slices(64) x 2 row-halves(64).
// A staged in LDS (atomic MALL reads); W streamed from L2 (plain cached).
__global__ __launch_bounds__(256, 1) void dgru3(
    const float* __restrict__ xf,
    const unsigned short* __restrict__ Wih_bf, const unsigned short* __restrict__ Whh_bf,
    const float* __restrict__ bih, const float* __restrict__ bhh,
    unsigned short* __restrict__ ring_bf, float* __restrict__ ring_f,
    unsigned short* __restrict__ hin_ring, float* __restrict__ out,
    unsigned* __restrict__ prog)
{
    __shared__ __align__(16) unsigned short sA[2][2][64][APAD];  // 69,632 B

    const int b = blockIdx.x;
    const int half  = b / 48;             // b and b+48 land on the same XCD (48%8==0)
    const int p     = b % 48;
    const int j     = p >> 3;
    const int layer = j >> 1;             // XCD (p&7) hosts 2 col-slices of each layer
    const int slice = (j & 1) * 8 + (p & 7);
    const int c0    = slice * 64;
    const int myidx = slice * 2 + half;
    const int rbase = half * 64;

    const int tid = threadIdx.x;
    const int wave = tid >> 6, lane = tid & 63;
    const int r15 = lane & 15, kq = lane >> 4, kq8 = kq * 8;
    const int wrow = (wave >> 1) * 32;    // local rows (0|32)
    const int wcol = (wave & 1) * 32;     // local cols (0|32); wave-pairs share W via L1

    const unsigned short* Wl_ih = Wih_bf + (size_t)layer * 3 * D * D;
    const unsigned short* Wl_hh = Whh_bf + (size_t)layer * 3 * D * D;
    const unsigned short* msrc[6] = { Wl_ih, Wl_ih + D * D, Wl_ih + 2 * D * D,
                                      Wl_hh, Wl_hh + D * D, Wl_hh + 2 * D * D };
    const int vcol0 = (c0 + wcol + r15) * D + kq8;
    const int vcol1 = vcol0 + 16 * D;

    float bs0[2], bs1[2], bi2c[2], bh2c[2];
    #pragma unroll
    for (int ct = 0; ct < 2; ++ct) {
        const int col = c0 + wcol + ct * 16 + r15;
        bs0[ct]  = bih[layer * 3 * D + col] + bhh[layer * 3 * D + col];
        bs1[ct]  = bih[layer * 3 * D + D + col] + bhh[layer * 3 * D + D + col];
        bi2c[ct] = bih[layer * 3 * D + 2 * D + col];
        bh2c[ct] = bhh[layer * 3 * D + 2 * D + col];
    }

    const int srow = tid >> 2;            // staging: 4 threads/row, 32 k each
    const int skp  = (tid & 3) * 32;
    const int sgoff = (rbase + srow) * D + skp;

    const int dil = 1 << layer, R = 2 << layer;
    const int rb = (layer == 0) ? 0 : (layer == 1) ? 2 : 6;

    unsigned* pr0 = prog;
    unsigned* pr1 = prog + 64;
    unsigned* pr2 = prog + 128;
    unsigned* myflag = prog + layer * 64 + myidx;
    const bool oddc = (r15 & 1);

    for (int t = 0; t < TT; ++t) {
        // ---- dataflow wait (point-to-point, no fences: all coherent reads are atomic)
        int th1, th2, th3; unsigned *a1, *a2, *a3;
        if (layer == 0)      { a1 = pr0; th1 = t;     a2 = pr1; th2 = t - 7; a3 = pr2; th3 = 0;     }
        else if (layer == 1) { a1 = pr0; th1 = t + 1; a2 = pr1; th2 = t - 1; a3 = pr2; th3 = t - 7; }
        else                 { a1 = pr1; th1 = t + 1; a2 = pr2; th2 = t - 3; a3 = pr2; th3 = 0;     }
        if (wave == 0) {
            const int fi = lane & 31;
            for (;;) {
                bool ok = true;
                if (th1 > 0) ok = ok && (int)AGLD(a1 + fi) >= th1;
                if (th2 > 0) ok = ok && (int)AGLD(a2 + fi) >= th2;
                if (th3 > 0) ok = ok && (int)AGLD(a3 + fi) >= th3;
                if (__all(ok)) break;
                __builtin_amdgcn_s_sleep(1);
            }
        }
        __syncthreads();

        const unsigned short* hinb = hin_ring + (size_t)((layer - 1) * 8 + (t & 7)) * BD; // layers 1,2
        const float* xt = xf + (size_t)t * BD;
        const int rs = (t + dil) % R, wsl = t % R;
        const unsigned short* hprevb = ring_bf + (size_t)(rb + rs) * BD;
        const float* hprevf = ring_f + (size_t)(rb + rs) * BD;
        float* houtf = ring_f + (size_t)(rb + wsl) * BD;
        unsigned short* houtb = ring_bf + (size_t)(rb + wsl) * BD;

        const ull* psrc = (const ull*)(hprevb + sgoff);
        const ull* hsrc = (layer == 0) ? (const ull*)0 : (const ull*)(hinb + sgoff);
        const float* xsrc = xt + sgoff;

        ull Sh[8], Sp[8];
        f32x4 acc[2][2][6] = {};
        bf16x8 W0[12], W1[12];
        float hpv[2][2][4]; unsigned rpk[2][2][4]; float rsl0[2][2][4];

        STAGE_ISSUE(0);
        STAGE_WRITE(0); LBAR;
        WISSUE(W0, 0);
        #pragma unroll 1
        for (int kc = 0; kc < 8; ++kc) {
            const int buf = kc & 1, k4 = kc * 4;
            if (kc < 7) { STAGE_ISSUE(kc + 1); }
            else        { EPI_ISSUE; }
            WISSUE(W1, k4 + 1); COMP(buf, 0, W0);
            WISSUE(W0, k4 + 2); COMP(buf, 1, W1);
            WISSUE(W1, k4 + 3); COMP(buf, 2, W0);
            if (kc < 7) {
                WISSUE(W0, k4 + 4); COMP(buf, 3, W1);
                STAGE_WRITE(buf ^ 1); LBAR;
            } else {
                COMP(buf, 3, W1);
            }
        }

        // ---- gates + residual; agent-scope stores (MALL-direct, cross-XCD coherent)
        #pragma unroll
        for (int ct = 0; ct < 2; ++ct)
        #pragma unroll
        for (int rt = 0; rt < 2; ++rt)
        #pragma unroll
        for (int q = 0; q < 4; ++q) {
            const size_t idx = (size_t)(rbase + wrow + rt * 16 + kq * 4 + q) * D +
                               (c0 + wcol + ct * 16 + r15);
            float xr = acc[rt][ct][0][q] + acc[rt][ct][3][q] + bs0[ct];
            float xz = acc[rt][ct][1][q] + acc[rt][ct][4][q] + bs1[ct];
            float rg = 1.f / (1.f + __expf(-xr));
            float zg = 1.f / (1.f + __expf(-xz));
            float ng = tanhf(acc[rt][ct][2][q] + bi2c[ct] + rg * (acc[rt][ct][5][q] + bh2c[ct]));
            float hp = hpv[ct][rt][q];
            float h  = (1.f - zg) * ng + zg * hp;
            float res = (layer == 0) ? rsl0[ct][rt][q]
                        : bf2f((unsigned short)(oddc ? (rpk[ct][rt][q] >> 16)
                                                     : (rpk[ct][rt][q] & 0xffffu)));
            float v = (h + res) * 0.70710678f;
            float y = v > 0.f ? v : 0.2f * v;
            AGST(&houtf[idx], h);
            AGST(&houtb[idx], f2bf(h));
            if (layer == 2) AGST(&out[(size_t)t * BD + idx], y);
            else            AGST(&hin_ring[(size_t)(layer * 8 + (t & 7)) * BD + idx], f2bf(y));
        }

        asm volatile("s_waitcnt vmcnt(0)");
        __syncthreads();
        if (tid == 0) {
            __builtin_amdgcn_fence(__ATOMIC_RELEASE, "agent");
            AGST(myflag, (unsigned)(t + 1));
        }
    }
}

extern "C" void kernel_launch(void* const* d_in, const int* in_sizes, int n_in,
                              void* d_out, int out_size, void* d_ws, size_t ws_size,
                              hipStream_t stream) {
    const float* x   = (const float*)d_in[0];
    const float* Wih = (const float*)d_in[1];
    const float* Whh = (const float*)d_in[2];
    const float* bih = (const float*)d_in[3];
    const float* bhh = (const float*)d_in[4];
    float* out = (float*)d_out;

    char* ws = (char*)d_ws;
    size_t off = 0;
    auto alloc = [&](size_t bytes) -> void* {
        void* p = ws + off;
        off += (bytes + 255) & ~(size_t)255;
        return p;
    };

    const int nW = 3 * 3 * D * D;  // 9,437,184 per tensor
    unsigned short* Wih_bf = (unsigned short*)alloc((size_t)nW * 2);
    unsigned short* Whh_bf = (unsigned short*)alloc((size_t)nW * 2);

    size_t zstart = off;
    unsigned short* ring_bf  = (unsigned short*)alloc((size_t)14 * BD * 2);
    float*          ring_f   = (float*)alloc((size_t)14 * BD * 4);
    unsigned short* hin_ring = (unsigned short*)alloc((size_t)16 * BD * 2);
    unsigned*       prog     = (unsigned*)alloc(1024);
    size_t zbytes = off - zstart;

    cvt_f32_bf16<<<nW / 8 / 256, 256, 0, stream>>>(Wih, Wih_bf, nW);
    cvt_f32_bf16<<<nW / 8 / 256, 256, 0, stream>>>(Whh, Whh_bf, nW);
    hipMemsetAsync(ws + zstart, 0, zbytes, stream);

    dgru3<<<96, 256, 0, stream>>>(
        x, Wih_bf, Whh_bf, bih, bhh,
        ring_bf, ring_f, hin_ring, out, prog);
}

// Round 9
// 5744.063 us; speedup vs baseline: 3.4632x; 3.4632x over previous
//
#include <hip/hip_runtime.h>
#include <hip/hip_bf16.h>

#define TT 256
#define D 1024
#define BD (128 * 1024)
#define NWPL 85
#define NWG 256
#define NUSED 255
#define ROWLEN 1048

typedef __attribute__((ext_vector_type(8))) short bf16x8;
typedef __attribute__((ext_vector_type(4))) float f32x4;

__device__ __forceinline__ unsigned short f2bf(float f) {
    __hip_bfloat16 h = __float2bfloat16(f);
    return *reinterpret_cast<unsigned short*>(&h);
}
__device__ __forceinline__ float bf2f(unsigned short u) {
    unsigned v = (unsigned)u << 16;
    return __builtin_bit_cast(float, v);
}

__global__ __launch_bounds__(256) void cvt_f32_bf16(const float* __restrict__ in,
                                                    unsigned short* __restrict__ out, int n) {
    int i = (blockIdx.x * 256 + threadIdx.x) * 8;
    if (i + 8 <= n) {
        float4 a = *(const float4*)(in + i);
        float4 b = *(const float4*)(in + i + 4);
        unsigned short t[8] = { f2bf(a.x), f2bf(a.y), f2bf(a.z), f2bf(a.w),
                                f2bf(b.x), f2bf(b.y), f2bf(b.z), f2bf(b.w) };
        *(uint4*)(out + i) = *(const uint4*)t;
    }
}

// Persistent point-to-point dataflow dilated-GRU.
// Rings are 32 slots/layer; consumers re-read an address only after 32 steps.
// Acquire fence every 16 steps (16 < 32 - dil) guarantees stale L1/L2 lines are
// invalidated between reuses, while leaving L2 intact for the A-broadcast the
// other 15 steps (XCD-wide L2 sharing of hin/hprev tiles).
__global__ __launch_bounds__(256, 1) void dgru_dataflow(
    const unsigned short* __restrict__ xbf,
    const float* __restrict__ Wih, const float* __restrict__ Whh,
    const float* __restrict__ bih, const float* __restrict__ bhh,
    unsigned short* __restrict__ ring_bf,   // [3][32][BD] bf16 h history ring
    float* __restrict__ ring_f,             // [3][32][BD] f32 h ring (epilogue hp)
    unsigned short* __restrict__ hin_ring,  // [2][32][BD] bf16 y ring
    float* __restrict__ out,
    unsigned* __restrict__ prog)
{
    __shared__ unsigned short wlds[78 * ROWLEN];

    const int grp = blockIdx.x & 7;
    const int p = 32 * grp + (blockIdx.x >> 3);  // XCD-packing heuristic (perf only)
    if (p >= NUSED) return;
    const int layer = p / NWPL;
    const int u     = p % NWPL;
    const int ncols = (u < 4) ? 13 : 12;
    const int c0    = u * 12 + (u < 4 ? u : 4);

    // ---- one-time: weight slice fp32 -> bf16 -> LDS (stationary)
    {
        const float* w0 = Wih + (size_t)layer * 3 * D * D;
        const float* w1 = Whh + (size_t)layer * 3 * D * D;
        const int nrows = 6 * ncols;
        for (int rid = 0; rid < nrows; ++rid) {
            int m   = rid / (3 * ncols);
            int rem = rid - m * 3 * ncols;
            int g   = rem / ncols;
            int c   = rem - g * ncols;
            const float* src = (m ? w1 : w0) + ((size_t)g * D + c0 + c) * D + threadIdx.x * 4;
            float4 v = *(const float4*)src;
            ushort4 o = { f2bf(v.x), f2bf(v.y), f2bf(v.z), f2bf(v.w) };
            *(ushort4*)&wlds[rid * ROWLEN + threadIdx.x * 4] = o;
        }
        __syncthreads();
    }

    const int tid  = threadIdx.x;
    const int wave = tid >> 6;
    const int lane = tid & 63;
    const int r15  = lane & 15;
    const int kq   = lane >> 4;
    const int kq8  = kq * 8;
    const int c_cl = (r15 < ncols) ? r15 : (ncols - 1);
    const bool cvalid = r15 < ncols;
    const int col  = c0 + c_cl;

    const float bi2 = bih[layer * 3 * D + 2 * D + col];
    const float bh2 = bhh[layer * 3 * D + 2 * D + col];
    const float bs0 = bih[layer * 3 * D + col] + bhh[layer * 3 * D + col];
    const float bs1 = bih[layer * 3 * D + D + col] + bhh[layer * 3 * D + D + col];

    const unsigned short* bp[6];
    #pragma unroll
    for (int mg = 0; mg < 6; ++mg) bp[mg] = wlds + (mg * ncols + c_cl) * ROWLEN;

    const int arow_off0 = (wave * 32 + r15) * D;
    const int arow_off1 = (wave * 32 + 16 + r15) * D;

    const int dil = 1 << layer;

    unsigned* pr0 = prog;
    unsigned* pr1 = prog + 128;
    unsigned* pr2 = prog + 256;
    unsigned* myflag = prog + layer * 128 + u;

    const int j2 = (lane < 21) ? lane + 64 : lane;   // lanes cover flags [0,85) x2

    for (int t = 0; t < TT; ++t) {
        // thresholds: hin-ready / hprev-ready (peer coupling) / 32-slot back-pressure
        int th1, th2, th3; unsigned *a1, *a2, *a3;
        if (layer == 0)      { a1 = pr0; th1 = t;     a2 = pr1; th2 = t - 30; a3 = pr2; th3 = 0;      }
        else if (layer == 1) { a1 = pr0; th1 = t + 1; a2 = pr1; th2 = t - 1;  a3 = pr2; th3 = t - 30; }
        else                 { a1 = pr1; th1 = t + 1; a2 = pr2; th2 = t - 3;  a3 = pr2; th3 = 0;      }

        if (wave == 0) {
            for (;;) {
                bool ok = true;
                if (th1 > 0) ok = ok && (int)__hip_atomic_load(a1 + lane, __ATOMIC_RELAXED, __HIP_MEMORY_SCOPE_AGENT) >= th1
                                     && (int)__hip_atomic_load(a1 + j2,   __ATOMIC_RELAXED, __HIP_MEMORY_SCOPE_AGENT) >= th1;
                if (th2 > 0) ok = ok && (int)__hip_atomic_load(a2 + lane, __ATOMIC_RELAXED, __HIP_MEMORY_SCOPE_AGENT) >= th2
                                     && (int)__hip_atomic_load(a2 + j2,   __ATOMIC_RELAXED, __HIP_MEMORY_SCOPE_AGENT) >= th2;
                if (th3 > 0) ok = ok && (int)__hip_atomic_load(a3 + lane, __ATOMIC_RELAXED, __HIP_MEMORY_SCOPE_AGENT) >= th3
                                     && (int)__hip_atomic_load(a3 + j2,   __ATOMIC_RELAXED, __HIP_MEMORY_SCOPE_AGENT) >= th3;
                if (__all(ok)) break;
                __builtin_amdgcn_s_sleep(1);
            }
            // periodic invalidate: window 16 < ring(32) - dil => reuse always fenced
            if ((t & 15) == 0)
                __builtin_amdgcn_fence(__ATOMIC_ACQUIRE, "agent");
        }
        __syncthreads();

        const unsigned short* hinb = layer ? hin_ring + (size_t)((layer - 1) * 32 + (t & 31)) * BD
                                           : xbf + (size_t)t * BD;
        const int rs = (t + 32 - dil) & 31, wsl = t & 31;
        const unsigned short* hprevb = ring_bf + (size_t)(layer * 32 + rs) * BD;
        const float*  hprevf = ring_f + (size_t)(layer * 32 + rs) * BD;
        float*        houtf  = ring_f + (size_t)(layer * 32 + wsl) * BD;
        unsigned short* houtb = ring_bf + (size_t)(layer * 32 + wsl) * BD;

        // ---- epilogue operand prefetch (plain cached; fresh by fence-interval)
        float hpv[8], rsv[8];
        #pragma unroll
        for (int rtl = 0; rtl < 2; ++rtl)
            #pragma unroll
            for (int q = 0; q < 4; ++q) {
                const int row = wave * 32 + rtl * 16 + kq * 4 + q;
                const size_t idx = (size_t)row * D + col;
                hpv[rtl * 4 + q] = hprevf[idx];
                rsv[rtl * 4 + q] = bf2f(hinb[idx]);
            }

        f32x4 acc[2][2][3] = {};
        bf16x8 A0[16], A1[16], A2[16];

#define ISSUE1(Av, KS, SL) { \
        Av[(SL) * 4 + 0] = *(const bf16x8*)(hinb   + arow_off0 + (KS) * 32 + kq8); \
        Av[(SL) * 4 + 1] = *(const bf16x8*)(hprevb + arow_off0 + (KS) * 32 + kq8); \
        Av[(SL) * 4 + 2] = *(const bf16x8*)(hinb   + arow_off1 + (KS) * 32 + kq8); \
        Av[(SL) * 4 + 3] = *(const bf16x8*)(hprevb + arow_off1 + (KS) * 32 + kq8); }
#define ISSUEG(Av, BASE) { ISSUE1(Av, (BASE) + 0, 0) ISSUE1(Av, (BASE) + 1, 1) \
                           ISSUE1(Av, (BASE) + 2, 2) ISSUE1(Av, (BASE) + 3, 3) \
                           __builtin_amdgcn_sched_barrier(0); }
#define COMPG(Av, BASE) { _Pragma("unroll") for (int kk = 0; kk < 4; ++kk) { \
        bf16x8 Bv[6]; \
        _Pragma("unroll") for (int mg = 0; mg < 6; ++mg) \
            Bv[mg] = *(const bf16x8*)(bp[mg] + ((BASE) + kk) * 32 + kq8); \
        _Pragma("unroll") for (int g = 0; g < 3; ++g) { \
            acc[0][0][g] = __builtin_amdgcn_mfma_f32_16x16x32_bf16(Av[kk * 4 + 0], Bv[g],     acc[0][0][g], 0, 0, 0); \
            acc[0][1][g] = __builtin_amdgcn_mfma_f32_16x16x32_bf16(Av[kk * 4 + 1], Bv[3 + g], acc[0][1][g], 0, 0, 0); \
            acc[1][0][g] = __builtin_amdgcn_mfma_f32_16x16x32_bf16(Av[kk * 4 + 2], Bv[g],     acc[1][0][g], 0, 0, 0); \
            acc[1][1][g] = __builtin_amdgcn_mfma_f32_16x16x32_bf16(Av[kk * 4 + 3], Bv[3 + g], acc[1][1][g], 0, 0, 0); } } \
        __builtin_amdgcn_sched_barrier(0); }

        ISSUEG(A0, 0);  ISSUEG(A1, 4);  ISSUEG(A2, 8);
        COMPG(A0, 0);   ISSUEG(A0, 12);
        COMPG(A1, 4);   ISSUEG(A1, 16);
        COMPG(A2, 8);   ISSUEG(A2, 20);
        COMPG(A0, 12);  ISSUEG(A0, 24);
        COMPG(A1, 16);  ISSUEG(A1, 28);
        COMPG(A2, 20);
        COMPG(A0, 24);
        COMPG(A1, 28);

        // ---- gates + residual; sc1 stores (MALL-direct, cross-XCD coherent)
        #pragma unroll
        for (int rtl = 0; rtl < 2; ++rtl) {
            #pragma unroll
            for (int q = 0; q < 4; ++q) {
                const int row = wave * 32 + rtl * 16 + kq * 4 + q;
                const size_t idx = (size_t)row * D + col;
                float xr = acc[rtl][0][0][q] + acc[rtl][1][0][q] + bs0;
                float xz = acc[rtl][0][1][q] + acc[rtl][1][1][q] + bs1;
                float rg = 1.f / (1.f + __expf(-xr));
                float zg = 1.f / (1.f + __expf(-xz));
                float ng = tanhf(acc[rtl][0][2][q] + bi2 + rg * (acc[rtl][1][2][q] + bh2));
                float hp = hpv[rtl * 4 + q];
                float h  = (1.f - zg) * ng + zg * hp;
                float v = (h + rsv[rtl * 4 + q]) * 0.70710678f;
                float y = v > 0.f ? v : 0.2f * v;
                if (cvalid) {
                    __hip_atomic_store(&houtf[idx], h, __ATOMIC_RELAXED, __HIP_MEMORY_SCOPE_AGENT);
                    __hip_atomic_store(&houtb[idx], f2bf(h), __ATOMIC_RELAXED, __HIP_MEMORY_SCOPE_AGENT);
                    if (layer == 2) {
                        __hip_atomic_store(&out[(size_t)t * BD + idx], y, __ATOMIC_RELAXED, __HIP_MEMORY_SCOPE_AGENT);
                    } else {
                        __hip_atomic_store(&hin_ring[(size_t)(layer * 32 + (t & 31)) * BD + idx],
                                           f2bf(y), __ATOMIC_RELAXED, __HIP_MEMORY_SCOPE_AGENT);
                    }
                }
            }
        }

        __syncthreads();  // each wave drains vmcnt(0) before barrier => stores MALL-visible
        if (tid == 0) {
            __builtin_amdgcn_fence(__ATOMIC_RELEASE, "agent");
            __hip_atomic_store(myflag, (unsigned)(t + 1), __ATOMIC_RELAXED, __HIP_MEMORY_SCOPE_AGENT);
        }
    }
}

extern "C" void kernel_launch(void* const* d_in, const int* in_sizes, int n_in,
                              void* d_out, int out_size, void* d_ws, size_t ws_size,
                              hipStream_t stream) {
    const float* x   = (const float*)d_in[0];
    const float* Wih = (const float*)d_in[1];
    const float* Whh = (const float*)d_in[2];
    const float* bih = (const float*)d_in[3];
    const float* bhh = (const float*)d_in[4];
    float* out = (float*)d_out;

    char* ws = (char*)d_ws;
    size_t off = 0;
    auto alloc = [&](size_t bytes) -> void* {
        void* p = ws + off;
        off += (bytes + 255) & ~(size_t)255;
        return p;
    };

    const int NX = TT * BD;
    unsigned short* xbf = (unsigned short*)alloc((size_t)NX * 2);  // 67 MB

    size_t zstart = off;
    unsigned short* ring_bf  = (unsigned short*)alloc((size_t)96 * BD * 2);  // 25 MB
    float*          ring_f   = (float*)alloc((size_t)96 * BD * 4);           // 50 MB
    unsigned short* hin_ring = (unsigned short*)alloc((size_t)64 * BD * 2);  // 17 MB
    unsigned*       prog     = (unsigned*)alloc(2048);
    size_t zbytes = off - zstart;

    cvt_f32_bf16<<<NX / 8 / 256, 256, 0, stream>>>(x, xbf, NX);
    hipMemsetAsync(ws + zstart, 0, zbytes, stream);

    dgru_dataflow<<<NWG, 256, 0, stream>>>(
        xbf, Wih, Whh, bih, bhh,
        ring_bf, ring_f, hin_ring, out,
        prog);
}

// Round 10
// 5535.574 us; speedup vs baseline: 3.5937x; 1.0377x over previous
//
#include <hip/hip_runtime.h>
#include <hip/hip_bf16.h>

#define TT 256
#define D 1024
#define BD (128 * 1024)
#define NWPL 85
#define NWG 256
#define NUSED 255
#define ROWLEN 1048

typedef __attribute__((ext_vector_type(8))) short bf16x8;
typedef __attribute__((ext_vector_type(4))) float f32x4;

__device__ __forceinline__ unsigned short f2bf(float f) {
    __hip_bfloat16 h = __float2bfloat16(f);
    return *reinterpret_cast<unsigned short*>(&h);
}
__device__ __forceinline__ float bf2f(unsigned short u) {
    unsigned v = (unsigned)u << 16;
    return __builtin_bit_cast(float, v);
}

__global__ __launch_bounds__(256) void cvt_f32_bf16(const float* __restrict__ in,
                                                    unsigned short* __restrict__ out, int n) {
    int i = (blockIdx.x * 256 + threadIdx.x) * 8;
    if (i + 8 <= n) {
        float4 a = *(const float4*)(in + i);
        float4 b = *(const float4*)(in + i + 4);
        unsigned short t[8] = { f2bf(a.x), f2bf(a.y), f2bf(a.z), f2bf(a.w),
                                f2bf(b.x), f2bf(b.y), f2bf(b.z), f2bf(b.w) };
        *(uint4*)(out + i) = *(const uint4*)t;
    }
}

// Persistent point-to-point dataflow dilated-GRU, 8 waves/WG (2 waves/SIMD TLP).
// Wave w handles rows [w*16, w*16+16). Rings 32 slots; acquire fence every 16
// steps (16 < 32 - dil => stale lines always invalidated between reuses).
__global__ __launch_bounds__(512, 2) void dgru_dataflow(
    const unsigned short* __restrict__ xbf,
    const float* __restrict__ Wih, const float* __restrict__ Whh,
    const float* __restrict__ bih, const float* __restrict__ bhh,
    unsigned short* __restrict__ ring_bf,   // [3][32][BD]
    float* __restrict__ ring_f,             // [3][32][BD]
    unsigned short* __restrict__ hin_ring,  // [2][32][BD]
    float* __restrict__ out,
    unsigned* __restrict__ prog)
{
    __shared__ unsigned short wlds[78 * ROWLEN];

    const int grp = blockIdx.x & 7;
    const int p = 32 * grp + (blockIdx.x >> 3);  // XCD-packing heuristic (perf only)
    if (p >= NUSED) return;
    const int layer = p / NWPL;
    const int u     = p % NWPL;
    const int ncols = (u < 4) ? 13 : 12;
    const int c0    = u * 12 + (u < 4 ? u : 4);

    const int tid = threadIdx.x;

    // ---- one-time: weight slice fp32 -> bf16 -> LDS (stationary); 512 threads
    {
        const float* w0 = Wih + (size_t)layer * 3 * D * D;
        const float* w1 = Whh + (size_t)layer * 3 * D * D;
        const int nrows = 6 * ncols;
        const int rh   = tid >> 8;      // 0..1
        const int t255 = tid & 255;
        for (int rid = rh; rid < nrows; rid += 2) {
            int m   = rid / (3 * ncols);
            int rem = rid - m * 3 * ncols;
            int g   = rem / ncols;
            int c   = rem - g * ncols;
            const float* src = (m ? w1 : w0) + ((size_t)g * D + c0 + c) * D + t255 * 4;
            float4 v = *(const float4*)src;
            ushort4 o = { f2bf(v.x), f2bf(v.y), f2bf(v.z), f2bf(v.w) };
            *(ushort4*)&wlds[rid * ROWLEN + t255 * 4] = o;
        }
        __syncthreads();
    }

    const int wave = tid >> 6;          // 0..7, rows [wave*16, wave*16+16)
    const int lane = tid & 63;
    const int r15  = lane & 15;
    const int kq   = lane >> 4;
    const int kq8  = kq * 8;
    const int c_cl = (r15 < ncols) ? r15 : (ncols - 1);
    const bool cvalid = r15 < ncols;
    const int col  = c0 + c_cl;

    const float bi2 = bih[layer * 3 * D + 2 * D + col];
    const float bh2 = bhh[layer * 3 * D + 2 * D + col];
    const float bs0 = bih[layer * 3 * D + col] + bhh[layer * 3 * D + col];
    const float bs1 = bih[layer * 3 * D + D + col] + bhh[layer * 3 * D + D + col];

    const unsigned short* bp[6];
    #pragma unroll
    for (int mg = 0; mg < 6; ++mg) bp[mg] = wlds + (mg * ncols + c_cl) * ROWLEN;

    const int arow_off = (wave * 16 + r15) * D;

    const int dil = 1 << layer;

    unsigned* pr0 = prog;
    unsigned* pr1 = prog + 128;
    unsigned* pr2 = prog + 256;
    unsigned* myflag = prog + layer * 128 + u;

    const int j2 = (lane < 21) ? lane + 64 : lane;   // lanes cover flags [0,85) x2

    for (int t = 0; t < TT; ++t) {
        // thresholds: hin-ready / hprev-ready / 32-slot back-pressure
        int th1, th2, th3; unsigned *a1, *a2, *a3;
        if (layer == 0)      { a1 = pr0; th1 = t;     a2 = pr1; th2 = t - 30; a3 = pr2; th3 = 0;      }
        else if (layer == 1) { a1 = pr0; th1 = t + 1; a2 = pr1; th2 = t - 1;  a3 = pr2; th3 = t - 30; }
        else                 { a1 = pr1; th1 = t + 1; a2 = pr2; th2 = t - 3;  a3 = pr2; th3 = 0;      }

        if (wave == 0) {
            for (;;) {
                bool ok = true;
                if (th1 > 0) ok = ok && (int)__hip_atomic_load(a1 + lane, __ATOMIC_RELAXED, __HIP_MEMORY_SCOPE_AGENT) >= th1
                                     && (int)__hip_atomic_load(a1 + j2,   __ATOMIC_RELAXED, __HIP_MEMORY_SCOPE_AGENT) >= th1;
                if (th2 > 0) ok = ok && (int)__hip_atomic_load(a2 + lane, __ATOMIC_RELAXED, __HIP_MEMORY_SCOPE_AGENT) >= th2
                                     && (int)__hip_atomic_load(a2 + j2,   __ATOMIC_RELAXED, __HIP_MEMORY_SCOPE_AGENT) >= th2;
                if (th3 > 0) ok = ok && (int)__hip_atomic_load(a3 + lane, __ATOMIC_RELAXED, __HIP_MEMORY_SCOPE_AGENT) >= th3
                                     && (int)__hip_atomic_load(a3 + j2,   __ATOMIC_RELAXED, __HIP_MEMORY_SCOPE_AGENT) >= th3;
                if (__all(ok)) break;
                __builtin_amdgcn_s_sleep(1);
            }
            if ((t & 15) == 0)
                __builtin_amdgcn_fence(__ATOMIC_ACQUIRE, "agent");
        }
        __syncthreads();

        const unsigned short* hinb = layer ? hin_ring + (size_t)((layer - 1) * 32 + (t & 31)) * BD
                                           : xbf + (size_t)t * BD;
        const int rs = (t + 32 - dil) & 31, wsl = t & 31;
        const unsigned short* hprevb = ring_bf + (size_t)(layer * 32 + rs) * BD;
        const float*  hprevf = ring_f + (size_t)(layer * 32 + rs) * BD;
        float*        houtf  = ring_f + (size_t)(layer * 32 + wsl) * BD;
        unsigned short* houtb = ring_bf + (size_t)(layer * 32 + wsl) * BD;

        // ---- epilogue operand prefetch
        float hpv[4], rsv[4];
        #pragma unroll
        for (int q = 0; q < 4; ++q) {
            const int row = wave * 16 + kq * 4 + q;
            const size_t idx = (size_t)row * D + col;
            hpv[q] = hprevf[idx];
            rsv[q] = bf2f(hinb[idx]);
        }

        f32x4 acc[2][3] = {};
        bf16x8 A0[8], A1[8], A2[8];

#define ISSUE1(Av, KS, SL) { \
        Av[(SL) * 2 + 0] = *(const bf16x8*)(hinb   + arow_off + (KS) * 32 + kq8); \
        Av[(SL) * 2 + 1] = *(const bf16x8*)(hprevb + arow_off + (KS) * 32 + kq8); }
#define ISSUEG(Av, BASE) { ISSUE1(Av, (BASE) + 0, 0) ISSUE1(Av, (BASE) + 1, 1) \
                           ISSUE1(Av, (BASE) + 2, 2) ISSUE1(Av, (BASE) + 3, 3) \
                           __builtin_amdgcn_sched_barrier(0); }
#define COMPG(Av, BASE) { _Pragma("unroll") for (int kk = 0; kk < 4; ++kk) { \
        bf16x8 Bv[6]; \
        _Pragma("unroll") for (int mg = 0; mg < 6; ++mg) \
            Bv[mg] = *(const bf16x8*)(bp[mg] + ((BASE) + kk) * 32 + kq8); \
        _Pragma("unroll") for (int g = 0; g < 3; ++g) { \
            acc[0][g] = __builtin_amdgcn_mfma_f32_16x16x32_bf16(Av[kk * 2 + 0], Bv[g],     acc[0][g], 0, 0, 0); \
            acc[1][g] = __builtin_amdgcn_mfma_f32_16x16x32_bf16(Av[kk * 2 + 1], Bv[3 + g], acc[1][g], 0, 0, 0); } } \
        __builtin_amdgcn_sched_barrier(0); }

        ISSUEG(A0, 0);  ISSUEG(A1, 4);  ISSUEG(A2, 8);
        COMPG(A0, 0);   ISSUEG(A0, 12);
        COMPG(A1, 4);   ISSUEG(A1, 16);
        COMPG(A2, 8);   ISSUEG(A2, 20);
        COMPG(A0, 12);  ISSUEG(A0, 24);
        COMPG(A1, 16);  ISSUEG(A1, 28);
        COMPG(A2, 20);
        COMPG(A0, 24);
        COMPG(A1, 28);

        // ---- gates + residual; sc1 stores (MALL-direct, cross-XCD coherent)
        #pragma unroll
        for (int q = 0; q < 4; ++q) {
            const int row = wave * 16 + kq * 4 + q;
            const size_t idx = (size_t)row * D + col;
            float xr = acc[0][0][q] + acc[1][0][q] + bs0;
            float xz = acc[0][1][q] + acc[1][1][q] + bs1;
            float rg = 1.f / (1.f + __expf(-xr));
            float zg = 1.f / (1.f + __expf(-xz));
            float ng = tanhf(acc[0][2][q] + bi2 + rg * (acc[1][2][q] + bh2));
            float hp = hpv[q];
            float h  = (1.f - zg) * ng + zg * hp;
            float v = (h + rsv[q]) * 0.70710678f;
            float y = v > 0.f ? v : 0.2f * v;
            if (cvalid) {
                __hip_atomic_store(&houtf[idx], h, __ATOMIC_RELAXED, __HIP_MEMORY_SCOPE_AGENT);
                __hip_atomic_store(&houtb[idx], f2bf(h), __ATOMIC_RELAXED, __HIP_MEMORY_SCOPE_AGENT);
                if (layer == 2) {
                    __hip_atomic_store(&out[(size_t)t * BD + idx], y, __ATOMIC_RELAXED, __HIP_MEMORY_SCOPE_AGENT);
                } else {
                    __hip_atomic_store(&hin_ring[(size_t)(layer * 32 + (t & 31)) * BD + idx],
                                       f2bf(y), __ATOMIC_RELAXED, __HIP_MEMORY_SCOPE_AGENT);
                }
            }
        }

        __syncthreads();  // all 8 waves drain vmcnt(0) before publish
        if (tid == 0) {
            __builtin_amdgcn_fence(__ATOMIC_RELEASE, "agent");
            __hip_atomic_store(myflag, (unsigned)(t + 1), __ATOMIC_RELAXED, __HIP_MEMORY_SCOPE_AGENT);
        }
    }
}

extern "C" void kernel_launch(void* const* d_in, const int* in_sizes, int n_in,
                              void* d_out, int out_size, void* d_ws, size_t ws_size,
                              hipStream_t stream) {
    const float* x   = (const float*)d_in[0];
    const float* Wih = (const float*)d_in[1];
    const float* Whh = (const float*)d_in[2];
    const float* bih = (const float*)d_in[3];
    const float* bhh = (const float*)d_in[4];
    float* out = (float*)d_out;

    char* ws = (char*)d_ws;
    size_t off = 0;
    auto alloc = [&](size_t bytes) -> void* {
        void* p = ws + off;
        off += (bytes + 255) & ~(size_t)255;
        return p;
    };

    const int NX = TT * BD;
    unsigned short* xbf = (unsigned short*)alloc((size_t)NX * 2);  // 67 MB

    size_t zstart = off;
    unsigned short* ring_bf  = (unsigned short*)alloc((size_t)96 * BD * 2);  // 25 MB
    float*          ring_f   = (float*)alloc((size_t)96 * BD * 4);           // 50 MB
    unsigned short* hin_ring = (unsigned short*)alloc((size_t)64 * BD * 2);  // 17 MB
    unsigned*       prog     = (unsigned*)alloc(2048);
    size_t zbytes = off - zstart;

    cvt_f32_bf16<<<NX / 8 / 256, 256, 0, stream>>>(x, xbf, NX);
    hipMemsetAsync(ws + zstart, 0, zbytes, stream);

    dgru_dataflow<<<NWG, 512, 0, stream>>>(
        xbf, Wih, Whh, bih, bhh,
        ring_bf, ring_f, hin_ring, out,
        prog);
}